// Round 3
// baseline (470.901 us; speedup 1.0000x reference)
//
#include <hip/hip_runtime.h>
#include <hip/hip_bf16.h>
#include <math.h>

#define NB 8
#define INCH 512
#define OUTCH 256
#define SP 4096          // 64*64 spatial
#define LAT 512
#define NTAP 9
#define MDIM (NTAP*OUTCH)   // 2304

#define INV_SQRT_LAT 0.044194173824159216f   // 1/sqrt(512)
#define WSCALE 0.014731391274719738f         // 1/sqrt(512*9)

typedef __bf16 bf16x8 __attribute__((ext_vector_type(8)));
typedef float  f32x4  __attribute__((ext_vector_type(4)));

__device__ __forceinline__ unsigned short f2bf(float f) {
  unsigned u = __float_as_uint(f);
  u += 0x7fffu + ((u >> 16) & 1u);       // round-to-nearest-even
  return (unsigned short)(u >> 16);
}
__device__ __forceinline__ float bf2f(unsigned short v) {
  return __uint_as_float((unsigned)v << 16);
}

// ---------------- stage 0a: style[b,i] = w[b,:] @ aff[i,:] / sqrt(512) + bias[i]
__global__ void style_k(const float* __restrict__ w, const float* __restrict__ aff,
                        const float* __restrict__ bias, float* __restrict__ style) {
  int gid = blockIdx.x * 256 + threadIdx.x;       // 4096
  int b = gid >> 9, i = gid & 511;
  const float4* wv = (const float4*)(w + (size_t)b * LAT);
  const float4* av = (const float4*)(aff + (size_t)i * LAT);
  float s = 0.f;
#pragma unroll 4
  for (int l = 0; l < LAT / 4; ++l) {
    float4 a = av[l], ww = wv[l];
    s += a.x * ww.x + a.y * ww.y + a.z * ww.z + a.w * ww.w;
  }
  style[gid] = s * INV_SQRT_LAT + bias[i];
}

// ---------------- stage 0b: S[o,i] = scale^2 * sum_cd base^2 ; w9[tap][o][i] = bf16(scale*base)
__global__ void wprep_k(const float* __restrict__ cw, float* __restrict__ S,
                        unsigned short* __restrict__ w9) {
  int gid = blockIdx.x * 256 + threadIdx.x;       // 131072 = 256*512
  int o = gid >> 9, i = gid & 511;
  const float* p = cw + (size_t)gid * 9;          // gid == o*512+i, layout (o,i,3,3)
  float ss = 0.f, v[9];
#pragma unroll
  for (int t = 0; t < 9; ++t) { v[t] = p[t]; ss += v[t] * v[t]; }
  S[gid] = ss * (WSCALE * WSCALE);
#pragma unroll
  for (int t = 0; t < 9; ++t)
    w9[((size_t)(t * OUTCH + o)) * INCH + i] = f2bf(v[t] * WSCALE);
}

// ---------------- stage 0c: demod[b,o] = rsqrt(sum_i style^2 * S + 1e-8)
__global__ void demod_k(const float* __restrict__ style, const float* __restrict__ S,
                        float* __restrict__ dmod) {
  int gid = blockIdx.x * 256 + threadIdx.x;       // 2048
  int b = gid >> 8, o = gid & 255;
  const float4* sv = (const float4*)(style + (size_t)b * INCH);
  const float4* Sv = (const float4*)(S + (size_t)o * INCH);
  float acc = 0.f;
#pragma unroll 4
  for (int l = 0; l < INCH / 4; ++l) {
    float4 st = sv[l], s2 = Sv[l];
    acc += st.x * st.x * s2.x + st.y * st.y * s2.y + st.z * st.z * s2.z + st.w * st.w * s2.w;
  }
  dmod[gid] = 1.0f / sqrtf(acc + 1e-8f);
}

// ---------------- stage 0d: xmt[b][s][i] = bf16(x[b][i][s] * style[b][i])   (transpose)
__global__ void modx_k(const float* __restrict__ x, const float* __restrict__ style,
                       unsigned short* __restrict__ xmt) {
  __shared__ float tile[32][33];
  int b = blockIdx.z;
  int s0 = blockIdx.x * 32;
  int i0 = blockIdx.y * 32;
  int c = threadIdx.x & 31, r = threadIdx.x >> 5;   // 32 x 8
#pragma unroll
  for (int p = 0; p < 4; ++p) {
    int ii = r + p * 8;
    tile[ii][c] = x[((size_t)(b * INCH + i0 + ii)) * SP + s0 + c] * style[b * INCH + i0 + ii];
  }
  __syncthreads();
#pragma unroll
  for (int p = 0; p < 4; ++p) {
    int ss = r + p * 8;
    xmt[((size_t)(b * SP + s0 + ss)) * INCH + i0 + c] = f2bf(tile[c][ss]);
  }
}

// ---------------- stage 1: T[m, n] = sum_k A[m,k] * B[n,k]   (m97-style bf16 MFMA GEMM, B^T input)
// z-batched. M=2304 N=4096 K=512, tile 128x128, BK=64. Epilogue: LDS restage -> dwordx4 stores.
__global__ __launch_bounds__(256, 2)
void gemm_k(const unsigned short* __restrict__ A,   // MDIM x INCH
            const unsigned short* __restrict__ Bm,  // NB x SP x INCH
            unsigned short* __restrict__ C) {       // NB x MDIM x SP (bf16)
  __shared__ __align__(16) unsigned short As[128 * 64];
  __shared__ __align__(16) unsigned short Bs[128 * 64];
  __shared__ __align__(16) unsigned short stage[64 * 136];   // epilogue half-tile, stride 136
  Bm += (size_t)blockIdx.z * SP * INCH;
  C  += (size_t)blockIdx.z * MDIM * SP;
  const int tid  = threadIdx.x;
  const int lane = tid & 63;
  const int wave = tid >> 6;
  const int m0 = blockIdx.y * 128;
  const int n0 = blockIdx.x * 128;
  const int wm = (wave >> 1) * 64;
  const int wn = (wave & 1) * 64;
  const int lrow   = lane >> 3;             // 0..7
  const int gchunk = (lane & 7) ^ lrow;     // swizzled 16B chunk in global row

  f32x4 acc[4][4];
#pragma unroll
  for (int i = 0; i < 4; ++i)
#pragma unroll
    for (int j = 0; j < 4; ++j) acc[i][j] = (f32x4){0.f, 0.f, 0.f, 0.f};

  const int r16  = lane & 15;
  const int quad = lane >> 4;

  for (int k0 = 0; k0 < INCH; k0 += 64) {
#pragma unroll
    for (int it = 0; it < 4; ++it) {
      int rbase = it * 32 + wave * 8;
      const unsigned short* ga = A  + (size_t)(m0 + rbase + lrow) * INCH + k0 + gchunk * 8;
      const unsigned short* gb = Bm + (size_t)(n0 + rbase + lrow) * INCH + k0 + gchunk * 8;
      __builtin_amdgcn_global_load_lds((const __attribute__((address_space(1))) void*)ga,
                                       (__attribute__((address_space(3))) void*)&As[rbase * 64],
                                       16, 0, 0);
      __builtin_amdgcn_global_load_lds((const __attribute__((address_space(1))) void*)gb,
                                       (__attribute__((address_space(3))) void*)&Bs[rbase * 64],
                                       16, 0, 0);
    }
    __syncthreads();
#pragma unroll
    for (int kk = 0; kk < 2; ++kk) {
      bf16x8 af[4], bfr[4];
#pragma unroll
      for (int i = 0; i < 4; ++i) {
        int rowa = wm + i * 16 + r16;
        int cha  = (kk * 4 + quad) ^ (rowa & 7);
        af[i] = *(const bf16x8*)&As[rowa * 64 + cha * 8];
        int rowb = wn + i * 16 + r16;
        int chb  = (kk * 4 + quad) ^ (rowb & 7);
        bfr[i] = *(const bf16x8*)&Bs[rowb * 64 + chb * 8];
      }
#pragma unroll
      for (int i = 0; i < 4; ++i)
#pragma unroll
        for (int j = 0; j < 4; ++j)
          acc[i][j] = __builtin_amdgcn_mfma_f32_16x16x32_bf16(af[i], bfr[j], acc[i][j], 0, 0, 0);
    }
    __syncthreads();
  }
  // epilogue: C/D layout col=lane&15, row=quad*4+reg [m89]. Two half-tile passes via LDS.
  // stage col rotated by quad*8 (conflict-free b16 writes); reader un-rotates per row.
#pragma unroll
  for (int p = 0; p < 2; ++p) {
    if ((wave >> 1) == p) {
#pragma unroll
      for (int i = 0; i < 4; ++i) {
        int mr = i * 16 + quad * 4;           // local row within half-tile 0..63
#pragma unroll
        for (int j = 0; j < 4; ++j) {
          int ncb = ((wn + j * 16 + r16) + quad * 8) & 127;
#pragma unroll
          for (int r = 0; r < 4; ++r)
            stage[(mr + r) * 136 + ncb] = f2bf(acc[i][j][r]);
        }
      }
    }
    __syncthreads();
    {
      int lr = tid >> 2;                       // 0..63
      int qr = (lr >> 2) & 3;
      int quarter = tid & 3;                   // 32 cols each
      const unsigned short* srow = stage + lr * 136;
      size_t gbase = (size_t)(m0 + p * 64 + lr) * SP + n0 + quarter * 32;
#pragma unroll
      for (int k = 0; k < 4; ++k) {
        int lchunk = quarter * 4 + k;
        int pchunk = (lchunk + qr) & 15;
        uint4 val = *(const uint4*)(srow + pchunk * 8);
        *(uint4*)(&C[gbase + k * 8]) = val;
      }
    }
    __syncthreads();
  }
}

// ---------------- stage 2: separable parity-combine + 4x4 blur + demod
// Block = (strip of 16 Y-rows, o, b). Full 64-wide rows: coalesced tap loads.
// Tl (bf16, LDS): col 3 = x=-1, cols 4..67 = x 0..63, col 68 = x=64; row stride 78.
// V (fp32): [c][18 rows][128 xp], stride 136.
#define TLSTR 78
#define VSTR  136
__global__ __launch_bounds__(256)
void combine_k(const unsigned short* __restrict__ T, const float* __restrict__ dm,
               float* __restrict__ out) {
  __shared__ __align__(16) unsigned short TlB[9 * 18 * TLSTR + 8];
  __shared__ __align__(16) float V[3 * 18 * VSTR];
  T   += (size_t)blockIdx.z * MDIM * SP;
  dm  += (size_t)blockIdx.z * OUTCH;
  out += (size_t)blockIdx.z * OUTCH * 128 * 128;
  const int o  = blockIdx.y;
  const int Y0 = blockIdx.x * 16;
  const int tid = threadIdx.x;

  // zero-fill TlB (halo cols/rows must be 0)
  {
    uint4* tz = (uint4*)TlB;
#pragma unroll
    for (int idx = tid; idx < 1580; idx += 256) tz[idx] = (uint4){0u, 0u, 0u, 0u};
  }
  __syncthreads();

  // tap load: rows Y0-1 .. Y0+16, full width, 9 taps. 16 chunks of 4 elems per row.
  {
    const int c16 = tid & 15;
    const int r0  = tid >> 4;                 // 0..15
#pragma unroll
    for (int tap = 0; tap < 9; ++tap) {
      const unsigned short* tp = T + (size_t)(tap * OUTCH + o) * SP;
#pragma unroll
      for (int rr = 0; rr < 2; ++rr) {
        int ry = r0 + rr * 16;
        if (ry < 18) {
          int Yg = Y0 - 1 + ry;
          if ((unsigned)Yg < 64u) {
            ushort4 v4 = *(const ushort4*)(tp + Yg * 64 + c16 * 4);
            unsigned short* dst = &TlB[(tap * 18 + ry) * TLSTR + 4 + c16 * 4];
            *(ushort2*)(dst)     = make_ushort2(v4.x, v4.y);
            *(ushort2*)(dst + 2) = make_ushort2(v4.z, v4.w);
          }
        }
      }
    }
  }
  __syncthreads();

  // x-pass: 54 rows (c in 0..2, yr in 0..17) x 4 quarters of 16 X each -> V[c][yr][0..127]
  {
    const int r = tid >> 2;
    if (r < 54) {
      const int c  = r / 18;
      const int yr = r - c * 18;
      const int X0 = (tid & 3) * 16;
      float td[3][20];
#pragma unroll
      for (int d = 0; d < 3; ++d) {
        const unsigned short* src = &TlB[((c * 3 + d) * 18 + yr) * TLSTR + 2 + X0];
#pragma unroll
        for (int k = 0; k < 10; ++k) {
          ushort2 u2 = *(const ushort2*)(src + 2 * k);
          td[d][2 * k]     = bf2f(u2.x);
          td[d][2 * k + 1] = bf2f(u2.y);
        }
      }
      float vout[32];
#pragma unroll
      for (int Xl = 0; Xl < 16; ++Xl) {
        float a0 = td[0][Xl + 1], a1 = td[0][Xl + 2], a2 = td[0][Xl + 3];
        float b0 = td[1][Xl + 1], b1 = td[1][Xl + 2], b2 = td[1][Xl + 3];
        float c0 = td[2][Xl + 1], c1 = td[2][Xl + 2], c2 = td[2][Xl + 3];
        vout[2 * Xl]     = b0 + 3.f * c0 + 3.f * a1 + 3.f * b1 + c1 + a2;
        vout[2 * Xl + 1] = c0 + a1 + 3.f * b1 + 3.f * c1 + 3.f * a2 + b2;
      }
      float* vr = &V[(c * 18 + yr) * VSTR + 2 * X0];
#pragma unroll
      for (int q = 0; q < 8; ++q)
        *(f32x4*)(vr + 4 * q) = (f32x4){vout[4 * q], vout[4 * q + 1], vout[4 * q + 2], vout[4 * q + 3]};
    }
  }
  __syncthreads();

  // y-pass: 32 output rows x 128 cols, dwordx4 stores
  {
    const int y  = tid >> 3;        // 0..31
    const int py = y & 1;
    const int Yl = y >> 1;          // 0..15
    const int xq = (tid & 7) * 4;
    const float dmv = dm[o] * (1.0f / 16.0f);
    float* orow = out + ((size_t)o * 128 + (Y0 * 2 + y)) * 128;
#pragma unroll
    for (int xg = 0; xg < 4; ++xg) {
      int xp = xq + xg * 32;
      f32x4 v00 = *(const f32x4*)&V[(0 * 18 + Yl + 0) * VSTR + xp];
      f32x4 v01 = *(const f32x4*)&V[(0 * 18 + Yl + 1) * VSTR + xp];
      f32x4 v02 = *(const f32x4*)&V[(0 * 18 + Yl + 2) * VSTR + xp];
      f32x4 v10 = *(const f32x4*)&V[(1 * 18 + Yl + 0) * VSTR + xp];
      f32x4 v11 = *(const f32x4*)&V[(1 * 18 + Yl + 1) * VSTR + xp];
      f32x4 v12 = *(const f32x4*)&V[(1 * 18 + Yl + 2) * VSTR + xp];
      f32x4 v20 = *(const f32x4*)&V[(2 * 18 + Yl + 0) * VSTR + xp];
      f32x4 v21 = *(const f32x4*)&V[(2 * 18 + Yl + 1) * VSTR + xp];
      f32x4 v22 = *(const f32x4*)&V[(2 * 18 + Yl + 2) * VSTR + xp];
      f32x4 r;
      if (py == 0)
        r = v10 + 3.f * v20 + 3.f * v01 + 3.f * v11 + v21 + v02;
      else
        r = v20 + v01 + 3.f * v11 + 3.f * v21 + 3.f * v02 + v12;
      r *= dmv;
      *(f32x4*)(orow + xp) = r;
    }
  }
}

extern "C" void kernel_launch(void* const* d_in, const int* in_sizes, int n_in,
                              void* d_out, int out_size, void* d_ws, size_t ws_size,
                              hipStream_t stream) {
  const float* x    = (const float*)d_in[0];
  const float* w    = (const float*)d_in[1];
  const float* aff  = (const float*)d_in[2];
  const float* bias = (const float*)d_in[3];
  const float* cw   = (const float*)d_in[4];
  float* out = (float*)d_out;
  char* ws = (char*)d_ws;
  // ws layout: style 16K | S 512K | demod 8K | w9 2.25M | xmt 32M | T(bf16) 151M
  float* style        = (float*)(ws);
  float* S            = (float*)(ws + 16384);
  float* dmod         = (float*)(ws + 540672);
  unsigned short* w9  = (unsigned short*)(ws + 548864);
  unsigned short* xmt = (unsigned short*)(ws + 2908160);
  unsigned short* T   = (unsigned short*)(ws + 36462592);

  hipLaunchKernelGGL(style_k, dim3(16), dim3(256), 0, stream, w, aff, bias, style);
  hipLaunchKernelGGL(wprep_k, dim3(512), dim3(256), 0, stream, cw, S, w9);
  hipLaunchKernelGGL(demod_k, dim3(8), dim3(256), 0, stream, style, S, dmod);
  hipLaunchKernelGGL(modx_k, dim3(128, 16, 8), dim3(256), 0, stream, x, style, xmt);
  hipLaunchKernelGGL(gemm_k, dim3(32, 18, NB), dim3(256), 0, stream, w9, xmt, T);
  hipLaunchKernelGGL(combine_k, dim3(4, 256, NB), dim3(256), 0, stream, T, dmod, out);
}

// Round 4
// 401.335 us; speedup vs baseline: 1.1733x; 1.1733x over previous
//
#include <hip/hip_runtime.h>
#include <hip/hip_bf16.h>
#include <math.h>

#define NB 8
#define INCH 512
#define OUTCH 256
#define SP 4096          // 64*64 spatial
#define LAT 512
#define NTAP 9
#define MDIM (NTAP*OUTCH)   // 2304

#define INV_SQRT_LAT 0.044194173824159216f   // 1/sqrt(512)
#define WSCALE 0.014731391274719738f         // 1/sqrt(512*9)

typedef __bf16 bf16x8 __attribute__((ext_vector_type(8)));
typedef float  f32x4  __attribute__((ext_vector_type(4)));

__device__ __forceinline__ unsigned short f2bf(float f) {
  unsigned u = __float_as_uint(f);
  u += 0x7fffu + ((u >> 16) & 1u);       // round-to-nearest-even
  return (unsigned short)(u >> 16);
}
__device__ __forceinline__ float bf2f(unsigned short v) {
  return __uint_as_float((unsigned)v << 16);
}

// ---------------- stage 0a+0b fused: style GEMV (blocks 0..15) + weight prep (blocks 16..527)
__global__ void prep_k(const float* __restrict__ w, const float* __restrict__ aff,
                       const float* __restrict__ bias, float* __restrict__ style,
                       const float* __restrict__ cw, float* __restrict__ S,
                       unsigned short* __restrict__ w9) {
  if (blockIdx.x < 16) {
    int gid = blockIdx.x * 256 + threadIdx.x;       // 4096
    int b = gid >> 9, i = gid & 511;
    const float4* wv = (const float4*)(w + (size_t)b * LAT);
    const float4* av = (const float4*)(aff + (size_t)i * LAT);
    float s = 0.f;
#pragma unroll 4
    for (int l = 0; l < LAT / 4; ++l) {
      float4 a = av[l], ww = wv[l];
      s += a.x * ww.x + a.y * ww.y + a.z * ww.z + a.w * ww.w;
    }
    style[gid] = s * INV_SQRT_LAT + bias[i];
  } else {
    int gid = (blockIdx.x - 16) * 256 + threadIdx.x;  // 131072 = 256*512
    int o = gid >> 9, i = gid & 511;
    const float* p = cw + (size_t)gid * 9;            // layout (o,i,3,3)
    float ss = 0.f, v[9];
#pragma unroll
    for (int t = 0; t < 9; ++t) { v[t] = p[t]; ss += v[t] * v[t]; }
    S[gid] = ss * (WSCALE * WSCALE);
#pragma unroll
    for (int t = 0; t < 9; ++t)
      w9[((size_t)(t * OUTCH + o)) * INCH + i] = f2bf(v[t] * WSCALE);
  }
}

// ---------------- stage 0c: demod[b,o] = rsqrt(sum_i style^2 * S + 1e-8)
__global__ void demod_k(const float* __restrict__ style, const float* __restrict__ S,
                        float* __restrict__ dmod) {
  int gid = blockIdx.x * 256 + threadIdx.x;       // 2048
  int b = gid >> 8, o = gid & 255;
  const float4* sv = (const float4*)(style + (size_t)b * INCH);
  const float4* Sv = (const float4*)(S + (size_t)o * INCH);
  float acc = 0.f;
#pragma unroll 4
  for (int l = 0; l < INCH / 4; ++l) {
    float4 st = sv[l], s2 = Sv[l];
    acc += st.x * st.x * s2.x + st.y * st.y * s2.y + st.z * st.z * s2.z + st.w * st.w * s2.w;
  }
  dmod[gid] = 1.0f / sqrtf(acc + 1e-8f);
}

// ---------------- stage 0d: xmt[b][s][i] = bf16(x[b][i][s] * style[b][i])   (transpose)
__global__ void modx_k(const float* __restrict__ x, const float* __restrict__ style,
                       unsigned short* __restrict__ xmt) {
  __shared__ float tile[32][33];
  int b = blockIdx.z;
  int s0 = blockIdx.x * 32;
  int i0 = blockIdx.y * 32;
  int c = threadIdx.x & 31, r = threadIdx.x >> 5;   // 32 x 8
#pragma unroll
  for (int p = 0; p < 4; ++p) {
    int ii = r + p * 8;
    tile[ii][c] = x[((size_t)(b * INCH + i0 + ii)) * SP + s0 + c] * style[b * INCH + i0 + ii];
  }
  __syncthreads();
#pragma unroll
  for (int p = 0; p < 4; ++p) {
    int ss = r + p * 8;
    xmt[((size_t)(b * SP + s0 + ss)) * INCH + i0 + c] = f2bf(tile[c][ss]);
  }
}

// ---------------- stage 1: T[m, n] = sum_k A[m,k] * B[n,k]   (m97-style bf16 MFMA GEMM, B^T input)
// z-batched. M=2304 N=4096 K=512, tile 128x128, BK=64. Epilogue: LDS restage -> dwordx4 stores.
__global__ __launch_bounds__(256, 2)
void gemm_k(const unsigned short* __restrict__ A,   // MDIM x INCH
            const unsigned short* __restrict__ Bm,  // NB x SP x INCH
            unsigned short* __restrict__ C) {       // NB x MDIM x SP (bf16)
  __shared__ __align__(16) unsigned short As[128 * 64];
  __shared__ __align__(16) unsigned short Bs[128 * 64];
  __shared__ __align__(16) unsigned short stage[64 * 136];   // epilogue half-tile, stride 136
  Bm += (size_t)blockIdx.z * SP * INCH;
  C  += (size_t)blockIdx.z * MDIM * SP;
  const int tid  = threadIdx.x;
  const int lane = tid & 63;
  const int wave = tid >> 6;
  const int m0 = blockIdx.y * 128;
  const int n0 = blockIdx.x * 128;
  const int wm = (wave >> 1) * 64;
  const int wn = (wave & 1) * 64;
  const int lrow   = lane >> 3;             // 0..7
  const int gchunk = (lane & 7) ^ lrow;     // swizzled 16B chunk in global row

  f32x4 acc[4][4];
#pragma unroll
  for (int i = 0; i < 4; ++i)
#pragma unroll
    for (int j = 0; j < 4; ++j) acc[i][j] = (f32x4){0.f, 0.f, 0.f, 0.f};

  const int r16  = lane & 15;
  const int quad = lane >> 4;

  for (int k0 = 0; k0 < INCH; k0 += 64) {
#pragma unroll
    for (int it = 0; it < 4; ++it) {
      int rbase = it * 32 + wave * 8;
      const unsigned short* ga = A  + (size_t)(m0 + rbase + lrow) * INCH + k0 + gchunk * 8;
      const unsigned short* gb = Bm + (size_t)(n0 + rbase + lrow) * INCH + k0 + gchunk * 8;
      __builtin_amdgcn_global_load_lds((const __attribute__((address_space(1))) void*)ga,
                                       (__attribute__((address_space(3))) void*)&As[rbase * 64],
                                       16, 0, 0);
      __builtin_amdgcn_global_load_lds((const __attribute__((address_space(1))) void*)gb,
                                       (__attribute__((address_space(3))) void*)&Bs[rbase * 64],
                                       16, 0, 0);
    }
    __syncthreads();
#pragma unroll
    for (int kk = 0; kk < 2; ++kk) {
      bf16x8 af[4], bfr[4];
#pragma unroll
      for (int i = 0; i < 4; ++i) {
        int rowa = wm + i * 16 + r16;
        int cha  = (kk * 4 + quad) ^ (rowa & 7);
        af[i] = *(const bf16x8*)&As[rowa * 64 + cha * 8];
        int rowb = wn + i * 16 + r16;
        int chb  = (kk * 4 + quad) ^ (rowb & 7);
        bfr[i] = *(const bf16x8*)&Bs[rowb * 64 + chb * 8];
      }
#pragma unroll
      for (int i = 0; i < 4; ++i)
#pragma unroll
        for (int j = 0; j < 4; ++j)
          acc[i][j] = __builtin_amdgcn_mfma_f32_16x16x32_bf16(af[i], bfr[j], acc[i][j], 0, 0, 0);
    }
    __syncthreads();
  }
  // epilogue: C/D layout col=lane&15, row=quad*4+reg [m89]. Two half-tile passes via LDS.
#pragma unroll
  for (int p = 0; p < 2; ++p) {
    if ((wave >> 1) == p) {
#pragma unroll
      for (int i = 0; i < 4; ++i) {
        int mr = i * 16 + quad * 4;           // local row within half-tile 0..63
#pragma unroll
        for (int j = 0; j < 4; ++j) {
          int ncb = ((wn + j * 16 + r16) + quad * 8) & 127;
#pragma unroll
          for (int r = 0; r < 4; ++r)
            stage[(mr + r) * 136 + ncb] = f2bf(acc[i][j][r]);
        }
      }
    }
    __syncthreads();
    {
      int lr = tid >> 2;                       // 0..63
      int qr = (lr >> 2) & 3;
      int quarter = tid & 3;                   // 32 cols each
      const unsigned short* srow = stage + lr * 136;
      size_t gbase = (size_t)(m0 + p * 64 + lr) * SP + n0 + quarter * 32;
#pragma unroll
      for (int k = 0; k < 4; ++k) {
        int lchunk = quarter * 4 + k;
        int pchunk = (lchunk + qr) & 15;
        uint4 val = *(const uint4*)(srow + pchunk * 8);
        *(uint4*)(&C[gbase + k * 8]) = val;
      }
    }
    __syncthreads();
  }
}

// ---------------- stage 2: separable parity-combine + 4x4 blur + demod
// Block = (strip of 8 Y-rows, o, b). LDS 27.9KB -> 5 blocks/CU.
// TlB (bf16): rows (tap,ry) ry=0..9 (Yg=Y0-1..Y0+8), col 4 == x=0, stride 70.
// V (fp32): [c][10 rows][32 chunks of 4], stride 128 exactly, XOR chunk swizzle
//   p = (l & ~3) | ((l&3) ^ ((l>>3)&3))  -- conflict-free for both writers and readers.
#define STRIP 8
#define TLSTR 70
#define TLROWS 10
__global__ __launch_bounds__(256)
void combine_k(const unsigned short* __restrict__ T, const float* __restrict__ dm,
               float* __restrict__ out) {
  __shared__ __align__(16) unsigned short TlB[9 * TLROWS * TLSTR + 4];  // 12608 B
  __shared__ __align__(16) float V[3 * TLROWS * 128];                   // 15360 B
  T   += (size_t)blockIdx.z * MDIM * SP;
  dm  += (size_t)blockIdx.z * OUTCH;
  out += (size_t)blockIdx.z * OUTCH * 128 * 128;
  const int o  = blockIdx.y;
  const int Y0 = blockIdx.x * STRIP;
  const int tid = threadIdx.x;

  // zero-fill TlB (halo rows/cols must read 0)
  {
    uint4* tz = (uint4*)TlB;
#pragma unroll
    for (int idx = tid; idx < 788; idx += 256) tz[idx] = (uint4){0u, 0u, 0u, 0u};
  }
  __syncthreads();

  // tap load: 9 taps x 10 rows x 64 cols as ushort4 chunks; 1440 ops
  for (int idx = tid; idx < 1440; idx += 256) {
    int tap = idx / 160;
    int rem = idx - tap * 160;
    int ry  = rem >> 4;
    int c16 = rem & 15;
    int Yg = Y0 - 1 + ry;
    if ((unsigned)Yg < 64u) {
      ushort4 v4 = *(const ushort4*)(T + (size_t)(tap * OUTCH + o) * SP + Yg * 64 + c16 * 4);
      unsigned short* dst = &TlB[(tap * TLROWS + ry) * TLSTR + 4 + c16 * 4];
      *(ushort2*)(dst)     = make_ushort2(v4.x, v4.y);
      *(ushort2*)(dst + 2) = make_ushort2(v4.z, v4.w);
    }
  }
  __syncthreads();

  // x-pass: 30 row-tasks (c 0..2, yr 0..9) x 8 x-chunks of 8 -> V
  {
    const int r  = tid >> 3;
    const int xc = tid & 7;
    if (r < 30) {
      const int c  = r / 10;
      const int yr = r - c * 10;
      const int X0 = xc * 8;
      float td[3][12];
#pragma unroll
      for (int d = 0; d < 3; ++d) {
        const unsigned short* src = &TlB[((c * 3 + d) * TLROWS + yr) * TLSTR + 2 + X0];
#pragma unroll
        for (int k = 0; k < 6; ++k) {
          ushort2 u2 = *(const ushort2*)(src + 2 * k);
          td[d][2 * k]     = bf2f(u2.x);
          td[d][2 * k + 1] = bf2f(u2.y);
        }
      }
      float vout[16];
#pragma unroll
      for (int Xl = 0; Xl < 8; ++Xl) {
        float a0 = td[0][Xl + 1], a1 = td[0][Xl + 2], a2 = td[0][Xl + 3];
        float b0 = td[1][Xl + 1], b1 = td[1][Xl + 2], b2 = td[1][Xl + 3];
        float c0 = td[2][Xl + 1], c1 = td[2][Xl + 2], c2 = td[2][Xl + 3];
        vout[2 * Xl]     = b0 + 3.f * c0 + 3.f * a1 + 3.f * b1 + c1 + a2;
        vout[2 * Xl + 1] = c0 + a1 + 3.f * b1 + 3.f * c1 + 3.f * a2 + b2;
      }
      float* vr = &V[(c * TLROWS + yr) * 128];
#pragma unroll
      for (int j = 0; j < 4; ++j) {
        int l = 4 * xc + j;
        int p = (l & ~3) | ((l & 3) ^ ((l >> 3) & 3));
        *(f32x4*)(vr + p * 4) = (f32x4){vout[4 * j], vout[4 * j + 1], vout[4 * j + 2], vout[4 * j + 3]};
      }
    }
  }
  __syncthreads();

  // y-pass: 16 out rows x 32 chunks; thread = (y=tid>>4, chunk tid&15 + 16*xg)
  {
    const int y  = tid >> 4;        // 0..15
    const int py = y & 1;
    const int Yl = y >> 1;          // 0..7
    const float dmv = dm[o] * (1.0f / 16.0f);
    float* orow = out + ((size_t)o * 128 + (Y0 * 2 + y)) * 128;
#pragma unroll
    for (int xg = 0; xg < 2; ++xg) {
      int l = (tid & 15) + 16 * xg;
      int p = (l & ~3) | ((l & 3) ^ ((l >> 3) & 3));
      int off = p * 4;
      f32x4 v00 = *(const f32x4*)&V[((0 * TLROWS) + Yl + 0) * 128 + off];
      f32x4 v01 = *(const f32x4*)&V[((0 * TLROWS) + Yl + 1) * 128 + off];
      f32x4 v02 = *(const f32x4*)&V[((0 * TLROWS) + Yl + 2) * 128 + off];
      f32x4 v10 = *(const f32x4*)&V[((1 * TLROWS) + Yl + 0) * 128 + off];
      f32x4 v11 = *(const f32x4*)&V[((1 * TLROWS) + Yl + 1) * 128 + off];
      f32x4 v12 = *(const f32x4*)&V[((1 * TLROWS) + Yl + 2) * 128 + off];
      f32x4 v20 = *(const f32x4*)&V[((2 * TLROWS) + Yl + 0) * 128 + off];
      f32x4 v21 = *(const f32x4*)&V[((2 * TLROWS) + Yl + 1) * 128 + off];
      f32x4 v22 = *(const f32x4*)&V[((2 * TLROWS) + Yl + 2) * 128 + off];
      f32x4 r;
      if (py == 0)
        r = v10 + 3.f * v20 + 3.f * v01 + 3.f * v11 + v21 + v02;
      else
        r = v20 + v01 + 3.f * v11 + 3.f * v21 + 3.f * v02 + v12;
      r *= dmv;
      *(f32x4*)(orow + l * 4) = r;
    }
  }
}

extern "C" void kernel_launch(void* const* d_in, const int* in_sizes, int n_in,
                              void* d_out, int out_size, void* d_ws, size_t ws_size,
                              hipStream_t stream) {
  const float* x    = (const float*)d_in[0];
  const float* w    = (const float*)d_in[1];
  const float* aff  = (const float*)d_in[2];
  const float* bias = (const float*)d_in[3];
  const float* cw   = (const float*)d_in[4];
  float* out = (float*)d_out;
  char* ws = (char*)d_ws;
  // ws layout: style 16K | S 512K | demod 8K | w9 2.25M | xmt 32M | T(bf16) 151M
  float* style        = (float*)(ws);
  float* S            = (float*)(ws + 16384);
  float* dmod         = (float*)(ws + 540672);
  unsigned short* w9  = (unsigned short*)(ws + 548864);
  unsigned short* xmt = (unsigned short*)(ws + 2908160);
  unsigned short* T   = (unsigned short*)(ws + 36462592);

  hipLaunchKernelGGL(prep_k, dim3(528), dim3(256), 0, stream, w, aff, bias, style, cw, S, w9);
  hipLaunchKernelGGL(demod_k, dim3(8), dim3(256), 0, stream, style, S, dmod);
  hipLaunchKernelGGL(modx_k, dim3(128, 16, 8), dim3(256), 0, stream, x, style, xmt);
  hipLaunchKernelGGL(gemm_k, dim3(32, 18, NB), dim3(256), 0, stream, w9, xmt, T);
  hipLaunchKernelGGL(combine_k, dim3(64 / STRIP, 256, NB), dim3(256), 0, stream, T, dmod, out);
}